// Round 1
// baseline (529.211 us; speedup 1.0000x reference)
//
#include <hip/hip_runtime.h>
#include <math.h>

// Problem constants (fixed by the reference)
#define MM 12       // M
#define KK 2        // K
#define DD 512      // D
#define CIN 4096    // C_IN
#define NCLS 8
#define NV 16       // N (videos)
#define TT 32       // T
// Only row t=31 of the LSTM batch is ever used -> only nt = n*32+31 rows matter.

// ws layout (floats)
#define PART_F   0                    // 4 * 1024 * 192 = 786432 floats (split-K partials)
#define POOLED_F 786432               // 16*512
#define GX_F     794624               // 16*2048
#define LAST_F   827392               // 16*512
#define HBUF_F   835584               // 2*512
#define CTR_F    836608               // 1 uint (16B aligned)
#define ZERO_BYTE_OFF ((size_t)HBUF_F * 4)
#define ZERO_BYTE_LEN (4096 + 16)

// ---------------------------------------------------------------------------
// Kernel 1: split-K GEMM  node1_part[ks][o][j] = sum_{cc in chunk ks}
//              w_a[o,cc] * base_out[(n*32+31)*12+m, cc],  j = n*12+m
// Tiles: 64(o) x 64(j), K-chunks of 1024 (4 splits), staged 16 cc at a time.
// ---------------------------------------------------------------------------
__global__ __launch_bounds__(256) void k_gemm(const float* __restrict__ w_a,
                                              const float* __restrict__ base_out,
                                              float* __restrict__ part) {
    const int ks = blockIdx.x;   // 0..3
    const int ot = blockIdx.y;   // 0..15
    const int jt = blockIdx.z;   // 0..2
    const int tid = threadIdx.x;

    __shared__ __align__(16) float As[16][68];
    __shared__ __align__(16) float Bs[16][68];

    const int to = tid & 15;     // o micro index
    const int tj = tid >> 4;     // j micro index

    // staging roles
    const int lrow = tid >> 2;   // 0..63
    const int lq   = tid & 3;    // 0..3 (float4 quad within 16-cc stage)
    const size_t a_base = (size_t)(ot * 64 + lrow) * CIN;
    const int j_stage = jt * 64 + lrow;
    const int n_stage = j_stage / 12;
    const int m_stage = j_stage - n_stage * 12;
    const size_t b_base = (size_t)((n_stage * TT + 31) * MM + m_stage) * CIN;

    float acc[4][4];
#pragma unroll
    for (int i = 0; i < 4; ++i)
#pragma unroll
        for (int jj = 0; jj < 4; ++jj) acc[i][jj] = 0.f;

    int cc0 = ks * 1024;
    for (int it = 0; it < 64; ++it, cc0 += 16) {
        float4 av = *(const float4*)&w_a[a_base + cc0 + lq * 4];
        float4 bv = *(const float4*)&base_out[b_base + cc0 + lq * 4];
        __syncthreads();
        As[lq * 4 + 0][lrow] = av.x; As[lq * 4 + 1][lrow] = av.y;
        As[lq * 4 + 2][lrow] = av.z; As[lq * 4 + 3][lrow] = av.w;
        Bs[lq * 4 + 0][lrow] = bv.x; Bs[lq * 4 + 1][lrow] = bv.y;
        Bs[lq * 4 + 2][lrow] = bv.z; Bs[lq * 4 + 3][lrow] = bv.w;
        __syncthreads();
#pragma unroll
        for (int cl = 0; cl < 16; ++cl) {
            float4 a = *(const float4*)&As[cl][to * 4];
            float4 b = *(const float4*)&Bs[cl][tj * 4];
            acc[0][0] += a.x * b.x; acc[0][1] += a.x * b.y; acc[0][2] += a.x * b.z; acc[0][3] += a.x * b.w;
            acc[1][0] += a.y * b.x; acc[1][1] += a.y * b.y; acc[1][2] += a.y * b.z; acc[1][3] += a.y * b.w;
            acc[2][0] += a.z * b.x; acc[2][1] += a.z * b.y; acc[2][2] += a.z * b.z; acc[2][3] += a.z * b.w;
            acc[3][0] += a.w * b.x; acc[3][1] += a.w * b.y; acc[3][2] += a.w * b.z; acc[3][3] += a.w * b.w;
        }
    }

#pragma unroll
    for (int i = 0; i < 4; ++i) {
        const int o = ot * 64 + to * 4 + i;
#pragma unroll
        for (int jj = 0; jj < 4; ++jj) {
            const int j = jt * 64 + tj * 4 + jj;
            part[(size_t)ks * (1024 * 192) + (size_t)o * 192 + j] = acc[i][jj];
        }
    }
}

// ---------------------------------------------------------------------------
// Kernel 2: reduce split-K partials, contract with A=sum_p dist[n,31,p,k,:,:],
//           relu, mean over w -> pooled[n, c]
// One WG per n.
// ---------------------------------------------------------------------------
__global__ __launch_bounds__(256) void k_pool(const float* __restrict__ part,
                                              const float* __restrict__ dist,
                                              float* __restrict__ pooled) {
    const int n = blockIdx.x;
    const int tid = threadIdx.x;
    __shared__ float Asum[KK][MM][MM];

    const size_t dbase = (size_t)(n * TT + 31) * (3 * KK * MM * MM);
    for (int f = tid; f < KK * MM * MM; f += 256) {
        const int k = f / (MM * MM);
        const int rem = f - k * (MM * MM);
        float s = dist[dbase + 0 * (KK * MM * MM) + k * (MM * MM) + rem]
                + dist[dbase + 1 * (KK * MM * MM) + k * (MM * MM) + rem]
                + dist[dbase + 2 * (KK * MM * MM) + k * (MM * MM) + rem];
        Asum[k][rem / MM][rem % MM] = s;
    }
    __syncthreads();

    for (int c = tid; c < DD; c += 256) {
        float nd[KK][MM];
#pragma unroll
        for (int k = 0; k < KK; ++k)
#pragma unroll
            for (int v = 0; v < MM; ++v) {
                const size_t off = (size_t)(k * DD + c) * 192 + n * MM + v;
                nd[k][v] = part[off] + part[off + 1 * (1024 * 192)]
                         + part[off + 2 * (1024 * 192)] + part[off + 3 * (1024 * 192)];
            }
        float accm = 0.f;
#pragma unroll
        for (int w = 0; w < MM; ++w) {
            float sw = 0.f;
#pragma unroll
            for (int k = 0; k < KK; ++k)
#pragma unroll
                for (int v = 0; v < MM; ++v) sw += nd[k][v] * Asum[k][v][w];
            accm += fmaxf(sw, 0.f);
        }
        pooled[n * DD + c] = accm * (1.f / 12.f);
    }
}

// ---------------------------------------------------------------------------
// Kernel 3: gx[n, r] = pooled[n,:] . w_ih[r,:] + b_ih[r] + b_hh[r]
// Grid (8 rblocks, 16 n), 256 threads, one r per thread.
// ---------------------------------------------------------------------------
__global__ __launch_bounds__(256) void k_gx(const float* __restrict__ pooled,
                                            const float* __restrict__ w_ih,
                                            const float* __restrict__ b_ih,
                                            const float* __restrict__ b_hh,
                                            float* __restrict__ gx) {
    const int rb = blockIdx.x;   // 0..7
    const int n  = blockIdx.y;   // 0..15
    const int tid = threadIdx.x;
    __shared__ __align__(16) float ps[DD];
    if (tid < 128) ((float4*)ps)[tid] = ((const float4*)(pooled + n * DD))[tid];
    __syncthreads();

    const int r = rb * 256 + tid;
    const float4* wr = (const float4*)(w_ih + (size_t)r * DD);
    const float4* pv = (const float4*)ps;
    float acc = b_ih[r] + b_hh[r];
#pragma unroll 4
    for (int q = 0; q < DD / 4; ++q) {
        float4 a = wr[q], b = pv[q];
        acc += a.x * b.x + a.y * b.y + a.z * b.z + a.w * b.w;
    }
    gx[n * (4 * DD) + r] = acc;
}

// ---------------------------------------------------------------------------
// Kernel 4: persistent LSTM over 16 steps + final classifier.
// 128 WGs x 256 threads. WG wg owns h-dims [wg*4, wg*4+4); its 16 w_hh rows
// (4 gates x 4 dims) live in LDS. Device-scope spin barrier between steps.
// ---------------------------------------------------------------------------
__global__ __launch_bounds__(256) void k_lstm(const float* __restrict__ w_hh,
                                              const float* __restrict__ gx,
                                              const float* __restrict__ w_cls,
                                              const float* __restrict__ b_cls,
                                              float* __restrict__ h_buf,   // 2*512
                                              float* __restrict__ last,    // 16*512
                                              unsigned int* __restrict__ ctr,
                                              float* __restrict__ out) {
    const int wg = blockIdx.x;   // 0..127
    const int tid = threadIdx.x;

    __shared__ __align__(16) float whh_s[16][516];  // pad 516: breaks 4-way bank alias
    __shared__ __align__(16) float h_s[DD];
    __shared__ float dot_s[16];

    // load the 16 w_hh rows this WG needs: row_local = gate*4 + dl
    for (int f = tid; f < 16 * DD; f += 256) {
        const int rl = f >> 9, col = f & 511;
        const int gate = rl >> 2, dl = rl & 3;
        whh_s[rl][col] = w_hh[(size_t)(gate * DD + wg * 4 + dl) * DD + col];
    }

    float c_reg = 0.f;
    const int g = tid >> 4;      // row_local 0..15
    const int lj = tid & 15;     // d-chunk of 32

    for (int s = 0; s < NV; ++s) {
        // stage current h into LDS
        if (tid < 128) ((float4*)h_s)[tid] = ((const float4*)(h_buf + (s & 1) * DD))[tid];
        __syncthreads();

        // 16 row-dots, each split over 16 lanes (32 elems each)
        float p = 0.f;
        const float4* wrow = (const float4*)&whh_s[g][0];
        const float4* hv4 = (const float4*)h_s;
#pragma unroll
        for (int q = 0; q < 8; ++q) {
            float4 wv = wrow[lj * 8 + q];
            float4 hv = hv4[lj * 8 + q];
            p += wv.x * hv.x + wv.y * hv.y + wv.z * hv.z + wv.w * hv.w;
        }
#pragma unroll
        for (int off = 8; off; off >>= 1) p += __shfl_down(p, off, 16);
        if (lj == 0) dot_s[g] = p;
        __syncthreads();

        if (tid < 4) {
            const int dg = wg * 4 + tid;
            const float* gxs = gx + s * (4 * DD);
            const float pi = gxs[0 * DD + dg] + dot_s[0 + tid];
            const float pf = gxs[1 * DD + dg] + dot_s[4 + tid];
            const float pg = gxs[2 * DD + dg] + dot_s[8 + tid];
            const float po = gxs[3 * DD + dg] + dot_s[12 + tid];
            const float si = 1.f / (1.f + expf(-pi));
            const float sf = 1.f / (1.f + expf(-pf));
            const float so = 1.f / (1.f + expf(-po));
            c_reg = sf * c_reg + si * tanhf(pg);
            const float hn = so * tanhf(c_reg);
            h_buf[((s + 1) & 1) * DD + dg] = hn;
            last[s * DD + dg] = hn;
            __threadfence();   // make writes device-visible before barrier arrive
        }
        __syncthreads();

        if (tid == 0) {
            atomicAdd(ctr, 1u);
            const unsigned int target = 128u * (unsigned)(s + 1);
            while (__hip_atomic_load(ctr, __ATOMIC_ACQUIRE, __HIP_MEMORY_SCOPE_AGENT) < target) {
                __builtin_amdgcn_s_sleep(1);
            }
        }
        __syncthreads();
        __threadfence();   // acquire: don't let L1 serve stale h next step
    }

    // classifier: out[n, cl] = last[n,:] . w_cls[cl,:] + b_cls[cl]
    if (wg == 0 && tid < NV * NCLS) {
        const int n = tid >> 3, cl = tid & 7;
        const float4* lv = (const float4*)(last + n * DD);
        const float4* wv = (const float4*)(w_cls + (size_t)cl * DD);
        float acc = b_cls[cl];
#pragma unroll 4
        for (int q = 0; q < DD / 4; ++q) {
            float4 a = lv[q], b = wv[q];
            acc += a.x * b.x + a.y * b.y + a.z * b.z + a.w * b.w;
        }
        out[tid] = acc;
    }
}

extern "C" void kernel_launch(void* const* d_in, const int* in_sizes, int n_in,
                              void* d_out, int out_size, void* d_ws, size_t ws_size,
                              hipStream_t stream) {
    const float* base_out = (const float*)d_in[0];
    const float* dist     = (const float*)d_in[1];
    const float* w_a      = (const float*)d_in[2];
    const float* w_ih     = (const float*)d_in[3];
    const float* w_hh     = (const float*)d_in[4];
    const float* b_ih     = (const float*)d_in[5];
    const float* b_hh     = (const float*)d_in[6];
    const float* w_cls    = (const float*)d_in[7];
    const float* b_cls    = (const float*)d_in[8];
    float* out = (float*)d_out;

    float* ws = (float*)d_ws;
    float* part   = ws + PART_F;
    float* pooled = ws + POOLED_F;
    float* gx     = ws + GX_F;
    float* last   = ws + LAST_F;
    float* h_buf  = ws + HBUF_F;
    unsigned int* ctr = (unsigned int*)(ws + CTR_F);

    // zero h state + barrier counter (ws is poisoned 0xAA before every call)
    hipMemsetAsync((char*)d_ws + ZERO_BYTE_OFF, 0, ZERO_BYTE_LEN, stream);

    k_gemm<<<dim3(4, 16, 3), 256, 0, stream>>>(w_a, base_out, part);
    k_pool<<<dim3(16), 256, 0, stream>>>(part, dist, pooled);
    k_gx<<<dim3(8, 16), 256, 0, stream>>>(pooled, w_ih, b_ih, b_hh, gx);
    k_lstm<<<dim3(128), 256, 0, stream>>>(w_hh, gx, w_cls, b_cls, h_buf, last, ctr, out);
}

// Round 2
// 286.508 us; speedup vs baseline: 1.8471x; 1.8471x over previous
//
#include <hip/hip_runtime.h>
#include <math.h>

// Problem constants (fixed by the reference)
#define MM 12       // M
#define KK 2        // K
#define DD 512      // D
#define CIN 4096    // C_IN
#define NCLS 8
#define NV 16       // N (videos) == LSTM step count
#define TT 32       // T
// Only LSTM batch row t=31 is ever consumed (rows independent; out uses hs[:, -1, :]).

typedef unsigned long long u64;

// ws layout (floats)
#define PART_F   0                    // 4 * 192 * 1024 (split-K partials, [ks][j][o])
#define POOLED_F 786432               // 16*512
#define GX_F     794624               // 16*2048
#define SLOT_F   827392               // 16 steps * 512 dims * 2 (u64 tagged {h,tag})
// total = 843776 floats = 3.375 MB

// ---------------------------------------------------------------------------
// Kernel 1: split-K GEMM  part[ks][j][o] = sum_{cc in chunk ks}
//              w_a[o,cc] * base_out[(n*32+31)*12+m, cc],  j = n*12+m
// Tiles: 64(o) x 64(j), K-chunks of 1024 (4 splits), staged 16 cc at a time.
// Output transposed to [j][o] so k_pool reads are coalesced.
// ---------------------------------------------------------------------------
__global__ __launch_bounds__(256) void k_gemm(const float* __restrict__ w_a,
                                              const float* __restrict__ base_out,
                                              float* __restrict__ part) {
    const int ks = blockIdx.x;   // 0..3
    const int ot = blockIdx.y;   // 0..15
    const int jt = blockIdx.z;   // 0..2
    const int tid = threadIdx.x;

    __shared__ __align__(16) float As[16][68];
    __shared__ __align__(16) float Bs[16][68];

    const int to = tid & 15;     // o micro index
    const int tj = tid >> 4;     // j micro index

    // staging roles
    const int lrow = tid >> 2;   // 0..63
    const int lq   = tid & 3;    // 0..3 (float4 quad within 16-cc stage)
    const size_t a_base = (size_t)(ot * 64 + lrow) * CIN;
    const int j_stage = jt * 64 + lrow;
    const int n_stage = j_stage / 12;
    const int m_stage = j_stage - n_stage * 12;
    const size_t b_base = (size_t)((n_stage * TT + 31) * MM + m_stage) * CIN;

    float acc[4][4];
#pragma unroll
    for (int i = 0; i < 4; ++i)
#pragma unroll
        for (int jj = 0; jj < 4; ++jj) acc[i][jj] = 0.f;

    int cc0 = ks * 1024;
    for (int it = 0; it < 64; ++it, cc0 += 16) {
        float4 av = *(const float4*)&w_a[a_base + cc0 + lq * 4];
        float4 bv = *(const float4*)&base_out[b_base + cc0 + lq * 4];
        __syncthreads();
        As[lq * 4 + 0][lrow] = av.x; As[lq * 4 + 1][lrow] = av.y;
        As[lq * 4 + 2][lrow] = av.z; As[lq * 4 + 3][lrow] = av.w;
        Bs[lq * 4 + 0][lrow] = bv.x; Bs[lq * 4 + 1][lrow] = bv.y;
        Bs[lq * 4 + 2][lrow] = bv.z; Bs[lq * 4 + 3][lrow] = bv.w;
        __syncthreads();
#pragma unroll
        for (int cl = 0; cl < 16; ++cl) {
            float4 a = *(const float4*)&As[cl][to * 4];
            float4 b = *(const float4*)&Bs[cl][tj * 4];
            acc[0][0] += a.x * b.x; acc[0][1] += a.x * b.y; acc[0][2] += a.x * b.z; acc[0][3] += a.x * b.w;
            acc[1][0] += a.y * b.x; acc[1][1] += a.y * b.y; acc[1][2] += a.y * b.z; acc[1][3] += a.y * b.w;
            acc[2][0] += a.z * b.x; acc[2][1] += a.z * b.y; acc[2][2] += a.z * b.z; acc[2][3] += a.z * b.w;
            acc[3][0] += a.w * b.x; acc[3][1] += a.w * b.y; acc[3][2] += a.w * b.z; acc[3][3] += a.w * b.w;
        }
    }

    // transposed store: part[ks][j][o], vectorized over o (i runs inside a float4)
    const int o_base = ot * 64 + to * 4;
#pragma unroll
    for (int jj = 0; jj < 4; ++jj) {
        const int j = jt * 64 + tj * 4 + jj;
        float4 v = make_float4(acc[0][jj], acc[1][jj], acc[2][jj], acc[3][jj]);
        *(float4*)&part[(size_t)ks * (192 * 1024) + (size_t)j * 1024 + o_base] = v;
    }
}

// ---------------------------------------------------------------------------
// Kernel 2: reduce split-K partials, contract with A=sum_p dist[n,31,p,k,:,:],
//           relu, mean over w -> pooled[n, c].  One WG per n. Coalesced reads
//           from transposed part.
// ---------------------------------------------------------------------------
__global__ __launch_bounds__(256) void k_pool(const float* __restrict__ part,
                                              const float* __restrict__ dist,
                                              float* __restrict__ pooled) {
    const int n = blockIdx.x;
    const int tid = threadIdx.x;
    __shared__ float Asum[KK][MM][MM];

    const size_t dbase = (size_t)(n * TT + 31) * (3 * KK * MM * MM);
    for (int f = tid; f < KK * MM * MM; f += 256) {
        const int k = f / (MM * MM);
        const int rem = f - k * (MM * MM);
        float s = dist[dbase + 0 * (KK * MM * MM) + k * (MM * MM) + rem]
                + dist[dbase + 1 * (KK * MM * MM) + k * (MM * MM) + rem]
                + dist[dbase + 2 * (KK * MM * MM) + k * (MM * MM) + rem];
        Asum[k][rem / MM][rem % MM] = s;
    }
    __syncthreads();

    for (int c = tid; c < DD; c += 256) {
        float nd[KK][MM];
#pragma unroll
        for (int k = 0; k < KK; ++k)
#pragma unroll
            for (int v = 0; v < MM; ++v) {
                const size_t off = (size_t)(n * MM + v) * 1024 + (k * DD + c);
                nd[k][v] = part[off] + part[off + 1 * (192 * 1024)]
                         + part[off + 2 * (192 * 1024)] + part[off + 3 * (192 * 1024)];
            }
        float accm = 0.f;
#pragma unroll
        for (int w = 0; w < MM; ++w) {
            float sw = 0.f;
#pragma unroll
            for (int k = 0; k < KK; ++k)
#pragma unroll
                for (int v = 0; v < MM; ++v) sw += nd[k][v] * Asum[k][v][w];
            accm += fmaxf(sw, 0.f);
        }
        pooled[n * DD + c] = accm * (1.f / 12.f);
    }
}

// ---------------------------------------------------------------------------
// Kernel 3: gx[n, r] = pooled[n,:] . w_ih[r,:] + b_ih[r] + b_hh[r]
// 128 WGs; WG wg caches w_ih rows [16wg,16wg+16) in LDS (read ONCE device-
// wide), then one thread per (r,n) computes a full 512-dot.
// ---------------------------------------------------------------------------
__global__ __launch_bounds__(256) void k_gx(const float* __restrict__ pooled,
                                            const float* __restrict__ w_ih,
                                            const float* __restrict__ b_ih,
                                            const float* __restrict__ b_hh,
                                            float* __restrict__ gx) {
    const int wg = blockIdx.x;   // 0..127
    const int tid = threadIdx.x;
    __shared__ __align__(16) float w_s[16][516];  // pad: (516r)%32 = 4r -> 2-way max

    for (int f = tid; f < 16 * DD; f += 256) {
        const int r = f >> 9, col = f & 511;
        w_s[r][col] = w_ih[(size_t)(wg * 16 + r) * DD + col];
    }
    __syncthreads();

    const int r = tid & 15;      // local row
    const int n = tid >> 4;      // video
    const float4* wr = (const float4*)&w_s[r][0];
    const float4* pv = (const float4*)(pooled + n * DD);
    float acc = 0.f;
#pragma unroll 8
    for (int q = 0; q < DD / 4; ++q) {
        float4 a = wr[q], b = pv[q];
        acc += a.x * b.x + a.y * b.y + a.z * b.z + a.w * b.w;
    }
    const int row = wg * 16 + r;
    gx[n * (4 * DD) + row] = acc + b_ih[row] + b_hh[row];
}

// ---------------------------------------------------------------------------
// Kernel 4: LSTM via tagged dataflow (NO barrier, NO fences).
// 128 WGs x 256 threads. WG wg owns h-dims [4wg, 4wg+4) (16 w_hh rows in LDS).
// Each h element is published as a 64-bit relaxed agent-scope atomic
// {hi: float bits, lo: tag = s+1} into slot[s][d]. Consumers poll tags.
// Slots double as `last` for the classifier (WG 0 tail).
// ---------------------------------------------------------------------------
__global__ __launch_bounds__(256) void k_lstm(const float* __restrict__ w_hh,
                                              const float* __restrict__ gx,
                                              const float* __restrict__ w_cls,
                                              const float* __restrict__ b_cls,
                                              u64* __restrict__ slots,   // 16*512
                                              float* __restrict__ out) {
    const int wg = blockIdx.x;   // 0..127
    const int tid = threadIdx.x;

    __shared__ __align__(16) float whh_s[16][516];  // row stride 516: 4r bank shift
    __shared__ __align__(16) float h_s[DD];
    __shared__ float dot_s[16];

    // preload: row_local rl = gate*4 + dl -> w_hh[gate*512 + wg*4 + dl]
    for (int f = tid; f < 16 * DD; f += 256) {
        const int rl = f >> 9, col = f & 511;
        const int gate = rl >> 2, dl = rl & 3;
        whh_s[rl][col] = w_hh[(size_t)(gate * DD + wg * 4 + dl) * DD + col];
    }

    float c_reg = 0.f;
    const int rl = tid >> 4;     // row_local 0..15
    const int lj = tid & 15;     // slice lane

    for (int s = 0; s < NV; ++s) {
        // stage h_{s-1} into LDS (tagged poll; s==0 -> zeros)
        if (s == 0) {
            for (int d = tid; d < DD; d += 256) h_s[d] = 0.f;
        } else {
            const u64* slot = slots + (size_t)(s - 1) * DD;
            for (int d = tid; d < DD; d += 256) {
                u64 v;
                do {
                    v = __hip_atomic_load(&slot[d], __ATOMIC_RELAXED, __HIP_MEMORY_SCOPE_AGENT);
                } while ((unsigned)(v & 0xffffffffull) != (unsigned)s);
                union { unsigned u; float f; } cv; cv.u = (unsigned)(v >> 32);
                h_s[d] = cv.f;
            }
        }
        __syncthreads();   // also covers whh_s preload before first use

        // 16 row-dots; slices interleaved (float4 idx lj + 16q) -> <=2-way banks
        float p = 0.f;
        const float4* wrow = (const float4*)&whh_s[rl][0];
        const float4* hv4 = (const float4*)h_s;
#pragma unroll
        for (int q = 0; q < 8; ++q) {
            float4 wv = wrow[lj + 16 * q];
            float4 hv = hv4[lj + 16 * q];
            p += wv.x * hv.x + wv.y * hv.y + wv.z * hv.z + wv.w * hv.w;
        }
#pragma unroll
        for (int off = 8; off; off >>= 1) p += __shfl_down(p, off, 16);
        if (lj == 0) dot_s[rl] = p;
        __syncthreads();

        if (tid < 4) {
            const int dg = wg * 4 + tid;
            const float* gxs = gx + s * (4 * DD);
            const float pi = gxs[0 * DD + dg] + dot_s[0 + tid];
            const float pf = gxs[1 * DD + dg] + dot_s[4 + tid];
            const float pg = gxs[2 * DD + dg] + dot_s[8 + tid];
            const float po = gxs[3 * DD + dg] + dot_s[12 + tid];
            const float si = 1.f / (1.f + expf(-pi));
            const float sf = 1.f / (1.f + expf(-pf));
            const float so = 1.f / (1.f + expf(-po));
            c_reg = sf * c_reg + si * tanhf(pg);
            const float hn = so * tanhf(c_reg);
            union { float f; unsigned u; } hv_; hv_.f = hn;
            const u64 pack = ((u64)hv_.u << 32) | (u64)(unsigned)(s + 1);
            __hip_atomic_store(&slots[(size_t)s * DD + dg], pack,
                               __ATOMIC_RELAXED, __HIP_MEMORY_SCOPE_AGENT);
        }
        // no barrier needed: h_s is only overwritten after the post-dot sync
        // above; own-dim polls next step are satisfied once tid<4's store lands.
    }

    // classifier tail: out[n,cl] = slot[n,:] . w_cls[cl,:] + b_cls[cl]
    if (wg == 0) {
        __syncthreads();
        // reuse whh_s rows (stride 516 keeps banks spread) as h staging
        for (int f = tid; f < NV * DD; f += 256) {
            const int ss = f >> 9, d = f & 511;
            u64 v;
            do {
                v = __hip_atomic_load(&slots[(size_t)ss * DD + d],
                                      __ATOMIC_RELAXED, __HIP_MEMORY_SCOPE_AGENT);
            } while ((unsigned)(v & 0xffffffffull) != (unsigned)(ss + 1));
            union { unsigned u; float f; } cv; cv.u = (unsigned)(v >> 32);
            whh_s[ss][d] = cv.f;
        }
        __syncthreads();
        if (tid < NV * NCLS) {
            const int n = tid >> 3, cl = tid & 7;
            const float4* hv = (const float4*)&whh_s[n][0];
            const float4* wv = (const float4*)(w_cls + (size_t)cl * DD);
            float acc = b_cls[cl];
#pragma unroll 8
            for (int q = 0; q < DD / 4; ++q) {
                float4 a = hv[q], b = wv[q];
                acc += a.x * b.x + a.y * b.y + a.z * b.z + a.w * b.w;
            }
            out[tid] = acc;
        }
    }
}

extern "C" void kernel_launch(void* const* d_in, const int* in_sizes, int n_in,
                              void* d_out, int out_size, void* d_ws, size_t ws_size,
                              hipStream_t stream) {
    const float* base_out = (const float*)d_in[0];
    const float* dist     = (const float*)d_in[1];
    const float* w_a      = (const float*)d_in[2];
    const float* w_ih     = (const float*)d_in[3];
    const float* w_hh     = (const float*)d_in[4];
    const float* b_ih     = (const float*)d_in[5];
    const float* b_hh     = (const float*)d_in[6];
    const float* w_cls    = (const float*)d_in[7];
    const float* b_cls    = (const float*)d_in[8];
    float* out = (float*)d_out;

    float* ws = (float*)d_ws;
    float* part   = ws + PART_F;
    float* pooled = ws + POOLED_F;
    float* gx     = ws + GX_F;
    u64*   slots  = (u64*)(ws + SLOT_F);
    // No memset needed: tags self-validate (0xAAAAAAAA poison != 1..16),
    // h_0 = 0 is generated in-kernel.

    k_gemm<<<dim3(4, 16, 3), 256, 0, stream>>>(w_a, base_out, part);
    k_pool<<<dim3(16), 256, 0, stream>>>(part, dist, pooled);
    k_gx<<<dim3(128), 256, 0, stream>>>(pooled, w_ih, b_ih, b_hh, gx);
    k_lstm<<<dim3(128), 256, 0, stream>>>(w_hh, gx, w_cls, b_cls, slots, out);
}